// Round 13
// baseline (111.140 us; speedup 1.0000x reference)
//
#include <hip/hip_runtime.h>
#include <math.h>

typedef _Float16 v8h __attribute__((ext_vector_type(8)));
typedef float v4f __attribute__((ext_vector_type(4)));

constexpr int D      = 256;   // feature dim
constexpr int NTILE  = 64;    // 16-cand tiles (1024 / 16)
constexpr int KS     = 8;     // k-steps of 32 per tile
constexpr int TILE_B = 8192;  // bytes per tile image (16 cand x 256 d x 2B)
constexpr int WIN_B  = 16384; // staged window = 2 tiles
constexpr int HWIN   = 16;    // windows per codebook half (32 tiles)
#define GUARD 2.0f            // packed-score gap above which approx top1 is provably np's argmin

// ---- pre-pass: codewords -> fp16 image in per-wave-read frag order ----
__global__ void vq_prep(const float* __restrict__ cw, unsigned short* __restrict__ img) {
    int gid = blockIdx.x * 256 + threadIdx.x;   // 0..32767
    int t  = gid >> 9;
    int r  = gid & 511;
    int ks = r >> 6;
    int l  = r & 63;
    int cand = t * 16 + (l & 15);
    int k0   = ks * 32 + (l >> 4) * 8;
    const float* src = cw + (size_t)cand * D + k0;
    float4 t0 = *(const float4*)(src);
    float4 t1 = *(const float4*)(src + 4);
    v8h h;
    h[0] = (_Float16)t0.x; h[1] = (_Float16)t0.y;
    h[2] = (_Float16)t0.z; h[3] = (_Float16)t0.w;
    h[4] = (_Float16)t1.x; h[5] = (_Float16)t1.y;
    h[6] = (_Float16)t1.z; h[7] = (_Float16)t1.w;
    *(v8h*)((char*)img + (size_t)gid * 16) = h;
}

// ---- codeword squared norms (fp32; IDENTICAL to the round-1/5 code that passed) ----
__global__ void vq_csq(const float* __restrict__ cw, float* __restrict__ csq) {
    int k = blockIdx.x * blockDim.x + threadIdx.x;
    const float4* p = reinterpret_cast<const float4*>(cw + (size_t)k * D);
    float s = 0.f;
    #pragma unroll 8
    for (int i = 0; i < D / 4; ++i) {
        float4 v = p[i];
        s += v.x * v.x; s += v.y * v.y; s += v.z * v.z; s += v.w * v.w;
    }
    csq[k] = s;
}

// ---- approx phase: codebook split across blockIdx.y (2 halves) -> 4 blocks/CU.
// 32 rows/wave in regs (x(-2) fp16), B staged via global_load_lds double-buffer,
// window's 2 tiles interleaved (4 MFMA chains). Emits per-half packed top-4. ----
__launch_bounds__(256, 4)
__global__ void vq_mfma(const float* __restrict__ inp,
                        const unsigned short* __restrict__ img,
                        const float* __restrict__ csq,
                        int* __restrict__ pack,
                        float* __restrict__ xsqbuf) {
    __shared__ char smem[2][WIN_B];

    const int tid  = threadIdx.x;
    const int lane = tid & 63;
    const int w    = tid >> 6;              // wave 0..3
    const int lr   = lane & 15;
    const int q    = lane >> 4;             // k-chunk group
    const int hh   = blockIdx.y;            // codebook half (0/1)
    const int base = blockIdx.x * 128 + w * 32;
    const char* imgh = (const char*)img + (size_t)hh * 32 * TILE_B;

    // stage window 0 of this half FIRST so it overlaps the A-load/convert
    #pragma unroll
    for (int i = 0; i < 4; ++i) {
        int off = i * 4096 + w * 1024;
        __builtin_amdgcn_global_load_lds(
            (const __attribute__((address_space(1))) unsigned int*)(imgh + off + lane * 16),
            (__attribute__((address_space(3))) unsigned int*)(&smem[0][off]),
            16, 0, 0);
    }

    // load + convert A (pre-scaled by -2, exact); half 0 also emits exact f32 xsq
    v8h a2[2][8];
    #pragma unroll
    for (int m = 0; m < 2; ++m) {
        const float* rp = inp + (size_t)(base + m * 16 + lr) * D + q * 8;
        float sq = 0.f;
        #pragma unroll
        for (int ks = 0; ks < KS; ++ks) {
            float4 t0 = *(const float4*)(rp + ks * 32);
            float4 t1 = *(const float4*)(rp + ks * 32 + 4);
            sq = fmaf(t0.x, t0.x, sq); sq = fmaf(t0.y, t0.y, sq);
            sq = fmaf(t0.z, t0.z, sq); sq = fmaf(t0.w, t0.w, sq);
            sq = fmaf(t1.x, t1.x, sq); sq = fmaf(t1.y, t1.y, sq);
            sq = fmaf(t1.z, t1.z, sq); sq = fmaf(t1.w, t1.w, sq);
            v8h h;
            h[0] = (_Float16)(-2.f * t0.x); h[1] = (_Float16)(-2.f * t0.y);
            h[2] = (_Float16)(-2.f * t0.z); h[3] = (_Float16)(-2.f * t0.w);
            h[4] = (_Float16)(-2.f * t1.x); h[5] = (_Float16)(-2.f * t1.y);
            h[6] = (_Float16)(-2.f * t1.z); h[7] = (_Float16)(-2.f * t1.w);
            a2[m][ks] = h;
        }
        sq += __shfl_xor(sq, 16);
        sq += __shfl_xor(sq, 32);
        if (hh == 0 && q == 0) xsqbuf[base + m * 16 + lr] = sq;
    }

    const float BIGF = __uint_as_float(0x7F000000u);
    float v1[2][4], v2[2][4];
    #pragma unroll
    for (int m = 0; m < 2; ++m)
        #pragma unroll
        for (int r = 0; r < 4; ++r) { v1[m][r] = BIGF; v2[m][r] = BIGF; }

    asm volatile("s_waitcnt vmcnt(0)" ::: "memory");   // window 0 landed
    __builtin_amdgcn_s_barrier();
    __builtin_amdgcn_sched_barrier(0);

    int cur = 0;
    for (int win = 0; win < HWIN; ++win) {
        if (win + 1 < HWIN) {   // stage next window early; overlaps compute
            const char* srct = imgh + (size_t)(win + 1) * WIN_B;
            #pragma unroll
            for (int i = 0; i < 4; ++i) {
                int off = i * 4096 + w * 1024;
                __builtin_amdgcn_global_load_lds(
                    (const __attribute__((address_space(1))) unsigned int*)(srct + off + lane * 16),
                    (__attribute__((address_space(3))) unsigned int*)(&smem[cur ^ 1][off]),
                    16, 0, 0);
            }
        }
        const int tA = hh * 32 + 2 * win;
        const int tB = tA + 1;
        float cqA = csq[tA * 16 + lr] + 4096.f;
        float cqB = csq[tB * 16 + lr] + 4096.f;

        const char* bb = smem[cur];
        // both tiles of the window interleaved: 4 independent MFMA chains
        v4f aA0 = {cqA, cqA, cqA, cqA}; v4f aA1 = aA0;
        v4f aB0 = {cqB, cqB, cqB, cqB}; v4f aB1 = aB0;
        #pragma unroll
        for (int ks = 0; ks < KS; ++ks) {
            v8h bA = *(const v8h*)(bb + ks * 1024 + lane * 16);
            v8h bB = *(const v8h*)(bb + TILE_B + ks * 1024 + lane * 16);
            aA0 = __builtin_amdgcn_mfma_f32_16x16x32_f16(a2[0][ks], bA, aA0, 0, 0, 0);
            aB0 = __builtin_amdgcn_mfma_f32_16x16x32_f16(a2[0][ks], bB, aB0, 0, 0, 0);
            aA1 = __builtin_amdgcn_mfma_f32_16x16x32_f16(a2[1][ks], bA, aA1, 0, 0, 0);
            aB1 = __builtin_amdgcn_mfma_f32_16x16x32_f16(a2[1][ks], bB, aB1, 0, 0, 0);
        }
        // packed top-2 update (round-to-nearest monotone packing, idx in low 10b)
        unsigned idxA = (unsigned)(tA * 16) | (unsigned)lr;
        unsigned idxB = (unsigned)(tB * 16) | (unsigned)lr;
        #pragma unroll
        for (int r = 0; r < 4; ++r) {
            float f;
            f = __uint_as_float(((__float_as_uint(aA0[r]) + 0x200u) & 0xFFFFFC00u) | idxA);
            { float mx = fmaxf(v1[0][r], f); v2[0][r] = fminf(v2[0][r], mx); v1[0][r] = fminf(v1[0][r], f); }
            f = __uint_as_float(((__float_as_uint(aA1[r]) + 0x200u) & 0xFFFFFC00u) | idxA);
            { float mx = fmaxf(v1[1][r], f); v2[1][r] = fminf(v2[1][r], mx); v1[1][r] = fminf(v1[1][r], f); }
            f = __uint_as_float(((__float_as_uint(aB0[r]) + 0x200u) & 0xFFFFFC00u) | idxB);
            { float mx = fmaxf(v1[0][r], f); v2[0][r] = fminf(v2[0][r], mx); v1[0][r] = fminf(v1[0][r], f); }
            f = __uint_as_float(((__float_as_uint(aB1[r]) + 0x200u) & 0xFFFFFC00u) | idxB);
            { float mx = fmaxf(v1[1][r], f); v2[1][r] = fminf(v2[1][r], mx); v1[1][r] = fminf(v1[1][r], f); }
        }

        asm volatile("s_waitcnt vmcnt(0)" ::: "memory");   // next window landed
        __builtin_amdgcn_s_barrier();
        __builtin_amdgcn_sched_barrier(0);
        cur ^= 1;
    }

    // bitonic merge of packed sorted-2 (padded to 4) across the 16 lanes per row
    #pragma unroll
    for (int m = 0; m < 2; ++m)
        #pragma unroll
        for (int r = 0; r < 4; ++r) {
            float L0 = v1[m][r], L1 = v2[m][r], L2 = BIGF, L3 = BIGF;
            #pragma unroll
            for (int off = 8; off; off >>= 1) {
                float P0 = __shfl_xor(L0, off, 16);
                float P1 = __shfl_xor(L1, off, 16);
                float P2 = __shfl_xor(L2, off, 16);
                float P3 = __shfl_xor(L3, off, 16);
                float M0 = fminf(L0, P3), M1 = fminf(L1, P2);
                float M2 = fminf(L2, P1), M3 = fminf(L3, P0);
                float a0 = fminf(M0, M2), c0 = fmaxf(M0, M2);
                float b0 = fminf(M1, M3), d0 = fmaxf(M1, M3);
                L0 = fminf(a0, b0); L1 = fmaxf(a0, b0);
                L2 = fminf(c0, d0); L3 = fmaxf(c0, d0);
            }
            if (lr == 0) {
                int row = base + m * 16 + q * 4 + r;
                ((int4*)pack)[(size_t)row * 2 + hh] = make_int4(
                    (int)__float_as_uint(L0), (int)__float_as_uint(L1),
                    (int)__float_as_uint(L2), (int)__float_as_uint(L3));
            }
        }
}

// ---- output phase: merge the two per-half sorted top-4s (packed min/max
// network) -> global top-4. Clear rows (gap >= GUARD): winner = top1, loss
// from (s0-4096)+xsq. Near-tie rows: np-ordered exact 4-cand rescore
// (VERBATIM round-7 chain). Gather-write coalesced. ----
__launch_bounds__(256)
__global__ void vq_out(const float* __restrict__ inp,
                       const float* __restrict__ cw,
                       const float* __restrict__ csq,
                       const int* __restrict__ pack,
                       const float* __restrict__ xsqbuf,
                       float* __restrict__ outq,
                       float* __restrict__ outi,
                       float* __restrict__ bsum) {
    __shared__ float s_l[4];
    const int tid  = threadIdx.x;
    const int lane = tid & 63;
    const int wv   = tid >> 6;
    const int g    = blockIdx.x * 256 + tid;
    const int row  = g >> 2;        // 4 lanes per row
    const int c    = g & 3;

    int4 pa = ((const int4*)pack)[(size_t)row * 2 + 0];
    int4 pb = ((const int4*)pack)[(size_t)row * 2 + 1];
    // 4 smallest of the two sorted quads (bitonic merge, packed floats)
    float a0 = __uint_as_float((unsigned)pa.x), a1 = __uint_as_float((unsigned)pa.y);
    float a2 = __uint_as_float((unsigned)pa.z), a3 = __uint_as_float((unsigned)pa.w);
    float b0 = __uint_as_float((unsigned)pb.x), b1 = __uint_as_float((unsigned)pb.y);
    float b2 = __uint_as_float((unsigned)pb.z), b3 = __uint_as_float((unsigned)pb.w);
    float M0 = fminf(a0, b3), M1 = fminf(a1, b2), M2 = fminf(a2, b1), M3 = fminf(a3, b0);
    float t0 = fminf(M0, M2), t2 = fmaxf(M0, M2);
    float t1 = fminf(M1, M3), t3 = fmaxf(M1, M3);
    float L0 = fminf(t0, t1), L1 = fmaxf(t0, t1);
    float L2 = fminf(t2, t3), L3 = fmaxf(t2, t3);

    float xq = xsqbuf[row];                        // broadcast load (loss-only)

    int   bi;
    float bd;
    bool rescue = (L1 - L0) < GUARD;               // uniform across the 4-lane group
    if (rescue) {
        float Lc = (c == 0) ? L0 : (c == 1) ? L1 : (c == 2) ? L2 : L3;
        int cd = (int)(__float_as_uint(Lc) & 1023u);
        const float4* xp = (const float4*)(inp + (size_t)row * D);
        const float4* cp = (const float4*)(cw + (size_t)cd * D);
        float dot = 0.f, xsq = 0.f;
        #pragma unroll 8
        for (int i = 0; i < D / 4; ++i) {
            float4 xv = xp[i];
            float4 cv = cp[i];
            xsq = fmaf(xv.x, xv.x, xsq);
            xsq = fmaf(xv.y, xv.y, xsq);
            xsq = fmaf(xv.z, xv.z, xsq);
            xsq = fmaf(xv.w, xv.w, xsq);
            dot = fmaf(xv.x, cv.x, dot);
            dot = fmaf(xv.y, cv.y, dot);
            dot = fmaf(xv.z, cv.z, dot);
            dot = fmaf(xv.w, cv.w, dot);
        }
        float m2 = dot + dot;
        float t  = xsq - m2;
        float e  = t + csq[cd];
        bd = e; bi = cd;
        #pragma unroll
        for (int off = 1; off <= 2; off <<= 1) {
            float ev = __shfl_xor(bd, off, 4);
            int   iv = __shfl_xor(bi, off, 4);
            bool  tk = (ev < bd) || (ev == bd && iv < bi);
            bd = tk ? ev : bd;
            bi = tk ? iv : bi;
        }
    } else {
        bi = (int)(__float_as_uint(L0) & 1023u);
        bd = (L0 - 4096.f) + xq;                   // approx dist (loss only)
    }

    if (c == 0) outi[row] = (float)bi;

    float lc = (c == 0) ? bd : 0.f;
    #pragma unroll
    for (int off = 32; off; off >>= 1) lc += __shfl_xor(lc, off);
    if (lane == 0) s_l[wv] = lc;
    __syncthreads();
    if (tid == 0) bsum[blockIdx.x] = s_l[0] + s_l[1] + s_l[2] + s_l[3];

    // coalesced gather of winning codewords -> outq (wave handles its 16 rows)
    const int rowbase = blockIdx.x * 64 + wv * 16;
    #pragma unroll 4
    for (int rr = 0; rr < 16; ++rr) {
        int bw = __shfl(bi, rr * 4, 64);   // lanes rr*4..rr*4+3 hold identical bi
        float4 cv = *(const float4*)(cw + (size_t)bw * D + lane * 4);
        *(float4*)(outq + (size_t)(rowbase + rr) * D + lane * 4) = cv;
    }
}

// ---- deterministic loss reduction ----
__global__ void vq_finalize(const float* __restrict__ bsum, float* __restrict__ out_loss,
                            int nb, float scale) {
    __shared__ float s[4];
    int tid = threadIdx.x;
    float v = 0.f;
    for (int i = tid; i < nb; i += 256) v += bsum[i];
    #pragma unroll
    for (int off = 32; off; off >>= 1) v += __shfl_down(v, off, 64);
    if ((tid & 63) == 0) s[tid >> 6] = v;
    __syncthreads();
    if (tid == 0) out_loss[0] = (s[0] + s[1] + s[2] + s[3]) * scale;
}

extern "C" void kernel_launch(void* const* d_in, const int* in_sizes, int n_in,
                              void* d_out, int out_size, void* d_ws, size_t ws_size,
                              hipStream_t stream) {
    const float* inp = (const float*)d_in[0];
    const float* cw  = (const float*)d_in[1];
    float* out = (float*)d_out;
    const int N = in_sizes[0] / D;   // 65536
    const int K = in_sizes[1] / D;   // 1024

    char* ws = (char*)d_ws;
    unsigned short* img = (unsigned short*)ws;            // 512 KB fp16 image
    float* csq    = (float*)(ws + (size_t)K * D * 2);     // 4 KB
    float* bsum   = csq + K;                              // 4 KB (1024 partials)
    int*   pack   = (int*)(bsum + 1024);                  // N*32B = 2 MB
    float* xsqbuf = (float*)(pack + (size_t)N * 8);       // N*4B = 256 KB

    float* outq = out;
    float* outi = out + (size_t)N * D;
    float* outl = outi + N;

    vq_prep<<<dim3((K * 32) / 256), dim3(256), 0, stream>>>(cw, img);
    vq_csq<<<dim3(K / 256), dim3(256), 0, stream>>>(cw, csq);

    // 32 rows/wave, 128 rows/block, codebook split in 2 -> 1024 blocks (4/CU)
    vq_mfma<<<dim3(N / 128, 2), dim3(256), 0, stream>>>(inp, img, csq, pack, xsqbuf);
    // 4 lanes per row -> 4N threads -> N/64 blocks of 256 (4+ waves/SIMD)
    vq_out<<<dim3(N / 64), dim3(256), 0, stream>>>(inp, cw, csq, pack, xsqbuf,
                                                   outq, outi, bsum);
    vq_finalize<<<dim3(1), dim3(256), 0, stream>>>(bsum, outl, N / 64,
                                                   1.25f / ((float)N * (float)D));
}

// Round 14
// 96.578 us; speedup vs baseline: 1.1508x; 1.1508x over previous
//
#include <hip/hip_runtime.h>
#include <math.h>

typedef _Float16 v8h __attribute__((ext_vector_type(8)));
typedef float v4f __attribute__((ext_vector_type(4)));

constexpr int D      = 256;   // feature dim
constexpr int NTILE  = 64;    // 16-cand tiles (1024 / 16)
constexpr int KS     = 8;     // k-steps of 32 per tile
constexpr int TILE_B = 8192;  // bytes per tile image (16 cand x 256 d x 2B)
constexpr int WIN_B  = 16384; // staged window = 2 tiles
#define GUARD 2.0f            // packed-score gap above which approx top1 is provably np's argmin

// ---- pre-pass: codewords -> fp16 image in per-wave-read frag order ----
__global__ void vq_prep(const float* __restrict__ cw, unsigned short* __restrict__ img) {
    int gid = blockIdx.x * 256 + threadIdx.x;   // 0..32767
    int t  = gid >> 9;
    int r  = gid & 511;
    int ks = r >> 6;
    int l  = r & 63;
    int cand = t * 16 + (l & 15);
    int k0   = ks * 32 + (l >> 4) * 8;
    const float* src = cw + (size_t)cand * D + k0;
    float4 t0 = *(const float4*)(src);
    float4 t1 = *(const float4*)(src + 4);
    v8h h;
    h[0] = (_Float16)t0.x; h[1] = (_Float16)t0.y;
    h[2] = (_Float16)t0.z; h[3] = (_Float16)t0.w;
    h[4] = (_Float16)t1.x; h[5] = (_Float16)t1.y;
    h[6] = (_Float16)t1.z; h[7] = (_Float16)t1.w;
    *(v8h*)((char*)img + (size_t)gid * 16) = h;
}

// ---- codeword squared norms (fp32; IDENTICAL to the round-1/5 code that passed) ----
__global__ void vq_csq(const float* __restrict__ cw, float* __restrict__ csq) {
    int k = blockIdx.x * blockDim.x + threadIdx.x;
    const float4* p = reinterpret_cast<const float4*>(cw + (size_t)k * D);
    float s = 0.f;
    #pragma unroll 8
    for (int i = 0; i < D / 4; ++i) {
        float4 v = p[i];
        s += v.x * v.x; s += v.y * v.y; s += v.z * v.z; s += v.w * v.w;
    }
    csq[k] = s;
}

// ---- fused main: r12's approx loop (verbatim), then wave-local epilogue:
// clear rows (packed gap >= GUARD) take approx top1; near-tie rows run the
// VERBATIM round-7 np-ordered exact 4-cand rescore; gather + coalesced write. ----
__launch_bounds__(256, 2)
__global__ void vq_main(const float* __restrict__ inp,
                        const float* __restrict__ cw,
                        const unsigned short* __restrict__ img,
                        const float* __restrict__ csq,
                        float* __restrict__ outq,
                        float* __restrict__ outi,
                        float* __restrict__ bsum) {
    __shared__ char  smem[2][WIN_B];   // 32 KB staging
    __shared__ int4  s_pack[128];      // per-row packed top-4
    __shared__ float s_xsq[128];       // per-row exact fp32 |x|^2
    __shared__ int   s_win[128];       // per-row winner index
    __shared__ float s_l[4];

    const int tid  = threadIdx.x;
    const int lane = tid & 63;
    const int w    = tid >> 6;              // wave 0..3
    const int lr   = lane & 15;
    const int q    = lane >> 4;             // k-chunk group
    const int base = blockIdx.x * 128 + w * 32;

    // stage window 0 (tiles 0,1) FIRST so it overlaps the A-load/convert
    #pragma unroll
    for (int i = 0; i < 4; ++i) {
        int off = i * 4096 + w * 1024;
        __builtin_amdgcn_global_load_lds(
            (const __attribute__((address_space(1))) unsigned int*)((const char*)img + off + lane * 16),
            (__attribute__((address_space(3))) unsigned int*)(&smem[0][off]),
            16, 0, 0);
    }

    // load + convert A (pre-scaled by -2, exact); emit exact f32 xsq to LDS
    v8h a2[2][8];
    #pragma unroll
    for (int m = 0; m < 2; ++m) {
        const float* rp = inp + (size_t)(base + m * 16 + lr) * D + q * 8;
        float sq = 0.f;
        #pragma unroll
        for (int ks = 0; ks < KS; ++ks) {
            float4 t0 = *(const float4*)(rp + ks * 32);
            float4 t1 = *(const float4*)(rp + ks * 32 + 4);
            sq = fmaf(t0.x, t0.x, sq); sq = fmaf(t0.y, t0.y, sq);
            sq = fmaf(t0.z, t0.z, sq); sq = fmaf(t0.w, t0.w, sq);
            sq = fmaf(t1.x, t1.x, sq); sq = fmaf(t1.y, t1.y, sq);
            sq = fmaf(t1.z, t1.z, sq); sq = fmaf(t1.w, t1.w, sq);
            v8h h;
            h[0] = (_Float16)(-2.f * t0.x); h[1] = (_Float16)(-2.f * t0.y);
            h[2] = (_Float16)(-2.f * t0.z); h[3] = (_Float16)(-2.f * t0.w);
            h[4] = (_Float16)(-2.f * t1.x); h[5] = (_Float16)(-2.f * t1.y);
            h[6] = (_Float16)(-2.f * t1.z); h[7] = (_Float16)(-2.f * t1.w);
            a2[m][ks] = h;
        }
        // combine the 4 k-chunk partials (q-lanes) -> full xsq (loss-only use)
        sq += __shfl_xor(sq, 16);
        sq += __shfl_xor(sq, 32);
        if (q == 0) s_xsq[w * 32 + m * 16 + lr] = sq;
    }

    const float BIGF = __uint_as_float(0x7F000000u);
    float v1[2][4], v2[2][4];
    #pragma unroll
    for (int m = 0; m < 2; ++m)
        #pragma unroll
        for (int r = 0; r < 4; ++r) { v1[m][r] = BIGF; v2[m][r] = BIGF; }

    asm volatile("s_waitcnt vmcnt(0)" ::: "memory");   // window 0 landed
    __builtin_amdgcn_s_barrier();
    __builtin_amdgcn_sched_barrier(0);

    int cur = 0;
    for (int win = 0; win < NTILE / 2; ++win) {
        if (win + 1 < NTILE / 2) {   // stage next window early; overlaps compute
            const char* srct = (const char*)img + (size_t)(win + 1) * WIN_B;
            #pragma unroll
            for (int i = 0; i < 4; ++i) {
                int off = i * 4096 + w * 1024;
                __builtin_amdgcn_global_load_lds(
                    (const __attribute__((address_space(1))) unsigned int*)(srct + off + lane * 16),
                    (__attribute__((address_space(3))) unsigned int*)(&smem[cur ^ 1][off]),
                    16, 0, 0);
            }
        }
        float cqA = csq[(2 * win) * 16 + lr] + 4096.f;
        float cqB = csq[(2 * win + 1) * 16 + lr] + 4096.f;

        const char* bb = smem[cur];
        // both tiles of the window interleaved: 4 independent MFMA chains
        v4f aA0 = {cqA, cqA, cqA, cqA}; v4f aA1 = aA0;
        v4f aB0 = {cqB, cqB, cqB, cqB}; v4f aB1 = aB0;
        #pragma unroll
        for (int ks = 0; ks < KS; ++ks) {
            v8h bA = *(const v8h*)(bb + ks * 1024 + lane * 16);
            v8h bB = *(const v8h*)(bb + TILE_B + ks * 1024 + lane * 16);
            aA0 = __builtin_amdgcn_mfma_f32_16x16x32_f16(a2[0][ks], bA, aA0, 0, 0, 0);
            aB0 = __builtin_amdgcn_mfma_f32_16x16x32_f16(a2[0][ks], bB, aB0, 0, 0, 0);
            aA1 = __builtin_amdgcn_mfma_f32_16x16x32_f16(a2[1][ks], bA, aA1, 0, 0, 0);
            aB1 = __builtin_amdgcn_mfma_f32_16x16x32_f16(a2[1][ks], bB, aB1, 0, 0, 0);
        }
        // packed top-2 update (round-to-nearest monotone packing, idx in low 10b)
        unsigned idxA = (unsigned)((2 * win) * 16) | (unsigned)lr;
        unsigned idxB = (unsigned)((2 * win + 1) * 16) | (unsigned)lr;
        #pragma unroll
        for (int r = 0; r < 4; ++r) {
            float f;
            f = __uint_as_float(((__float_as_uint(aA0[r]) + 0x200u) & 0xFFFFFC00u) | idxA);
            { float mx = fmaxf(v1[0][r], f); v2[0][r] = fminf(v2[0][r], mx); v1[0][r] = fminf(v1[0][r], f); }
            f = __uint_as_float(((__float_as_uint(aA1[r]) + 0x200u) & 0xFFFFFC00u) | idxA);
            { float mx = fmaxf(v1[1][r], f); v2[1][r] = fminf(v2[1][r], mx); v1[1][r] = fminf(v1[1][r], f); }
            f = __uint_as_float(((__float_as_uint(aB0[r]) + 0x200u) & 0xFFFFFC00u) | idxB);
            { float mx = fmaxf(v1[0][r], f); v2[0][r] = fminf(v2[0][r], mx); v1[0][r] = fminf(v1[0][r], f); }
            f = __uint_as_float(((__float_as_uint(aB1[r]) + 0x200u) & 0xFFFFFC00u) | idxB);
            { float mx = fmaxf(v1[1][r], f); v2[1][r] = fminf(v2[1][r], mx); v1[1][r] = fminf(v1[1][r], f); }
        }

        asm volatile("s_waitcnt vmcnt(0)" ::: "memory");   // next window landed
        __builtin_amdgcn_s_barrier();
        __builtin_amdgcn_sched_barrier(0);
        cur ^= 1;
    }

    // bitonic merge of packed sorted-2 (padded to 4) across the 16 lanes per row
    #pragma unroll
    for (int m = 0; m < 2; ++m)
        #pragma unroll
        for (int r = 0; r < 4; ++r) {
            float L0 = v1[m][r], L1 = v2[m][r], L2 = BIGF, L3 = BIGF;
            #pragma unroll
            for (int off = 8; off; off >>= 1) {
                float P0 = __shfl_xor(L0, off, 16);
                float P1 = __shfl_xor(L1, off, 16);
                float P2 = __shfl_xor(L2, off, 16);
                float P3 = __shfl_xor(L3, off, 16);
                float M0 = fminf(L0, P3), M1 = fminf(L1, P2);
                float M2 = fminf(L2, P1), M3 = fminf(L3, P0);
                float a0 = fminf(M0, M2), c0 = fmaxf(M0, M2);
                float b0 = fminf(M1, M3), d0 = fmaxf(M1, M3);
                L0 = fminf(a0, b0); L1 = fmaxf(a0, b0);
                L2 = fminf(c0, d0); L3 = fmaxf(c0, d0);
            }
            if (lr == 0) {
                int rloc = m * 16 + q * 4 + r;         // 0..31 within wave
                s_pack[w * 32 + rloc] = make_int4(
                    (int)__float_as_uint(L0), (int)__float_as_uint(L1),
                    (int)__float_as_uint(L2), (int)__float_as_uint(L3));
            }
        }
    // wave-local LDS round-trip (writer == reader wave); compiler inserts lgkmcnt

    // ---- fused epilogue: 4 lanes per row over the wave's 32 rows ----
    const int c = lane & 3;
    float lacc = 0.f;
    #pragma unroll
    for (int h = 0; h < 2; ++h) {
        int rloc = h * 16 + (lane >> 2);               // 0..31 within wave
        int grow = base + rloc;
        int4 pk = s_pack[w * 32 + rloc];
        float L0 = __uint_as_float((unsigned)pk.x);
        float L1 = __uint_as_float((unsigned)pk.y);
        float L2 = __uint_as_float((unsigned)pk.z);
        float L3 = __uint_as_float((unsigned)pk.w);
        float xq = s_xsq[w * 32 + rloc];

        int   bi;
        float bd;
        bool rescue = (L1 - L0) < GUARD;               // uniform across the 4-lane group
        if (rescue) {
            float Lc = (c == 0) ? L0 : (c == 1) ? L1 : (c == 2) ? L2 : L3;
            int cd = (int)(__float_as_uint(Lc) & 1023u);
            const float4* xp = (const float4*)(inp + (size_t)grow * D);
            const float4* cp = (const float4*)(cw + (size_t)cd * D);
            float dot = 0.f, xsq = 0.f;
            #pragma unroll 8
            for (int i = 0; i < D / 4; ++i) {
                float4 xv = xp[i];
                float4 cv = cp[i];
                xsq = fmaf(xv.x, xv.x, xsq);
                xsq = fmaf(xv.y, xv.y, xsq);
                xsq = fmaf(xv.z, xv.z, xsq);
                xsq = fmaf(xv.w, xv.w, xsq);
                dot = fmaf(xv.x, cv.x, dot);
                dot = fmaf(xv.y, cv.y, dot);
                dot = fmaf(xv.z, cv.z, dot);
                dot = fmaf(xv.w, cv.w, dot);
            }
            float m2 = dot + dot;
            float t  = xsq - m2;
            float e  = t + csq[cd];
            bd = e; bi = cd;
            #pragma unroll
            for (int off = 1; off <= 2; off <<= 1) {
                float ev = __shfl_xor(bd, off, 4);
                int   iv = __shfl_xor(bi, off, 4);
                bool  tk = (ev < bd) || (ev == bd && iv < bi);
                bd = tk ? ev : bd;
                bi = tk ? iv : bi;
            }
        } else {
            bi = (int)(__float_as_uint(L0) & 1023u);
            bd = (L0 - 4096.f) + xq;                   // approx dist (loss only)
        }

        if (c == 0) { s_win[w * 32 + rloc] = bi; lacc += bd; }
    }

    // gather winning codewords (L2-resident) -> coalesced outq write
    #pragma unroll 4
    for (int rr = 0; rr < 32; ++rr) {
        int bw = s_win[w * 32 + rr];                   // wave-uniform broadcast
        float4 cv = *(const float4*)(cw + (size_t)bw * D + lane * 4);
        *(float4*)(outq + (size_t)(base + rr) * D + lane * 4) = cv;
        if (lane == 0) outi[base + rr] = (float)bw;
    }

    // block loss partial (deterministic)
    #pragma unroll
    for (int off = 32; off; off >>= 1) lacc += __shfl_xor(lacc, off);
    if (lane == 0) s_l[w] = lacc;
    __syncthreads();
    if (tid == 0) bsum[blockIdx.x] = s_l[0] + s_l[1] + s_l[2] + s_l[3];
}

// ---- deterministic loss reduction ----
__global__ void vq_finalize(const float* __restrict__ bsum, float* __restrict__ out_loss,
                            int nb, float scale) {
    __shared__ float s[4];
    int tid = threadIdx.x;
    float v = 0.f;
    for (int i = tid; i < nb; i += 256) v += bsum[i];
    #pragma unroll
    for (int off = 32; off; off >>= 1) v += __shfl_down(v, off, 64);
    if ((tid & 63) == 0) s[tid >> 6] = v;
    __syncthreads();
    if (tid == 0) out_loss[0] = (s[0] + s[1] + s[2] + s[3]) * scale;
}

extern "C" void kernel_launch(void* const* d_in, const int* in_sizes, int n_in,
                              void* d_out, int out_size, void* d_ws, size_t ws_size,
                              hipStream_t stream) {
    const float* inp = (const float*)d_in[0];
    const float* cw  = (const float*)d_in[1];
    float* out = (float*)d_out;
    const int N = in_sizes[0] / D;   // 65536
    const int K = in_sizes[1] / D;   // 1024

    char* ws = (char*)d_ws;
    unsigned short* img = (unsigned short*)ws;            // 512 KB fp16 image
    float* csq  = (float*)(ws + (size_t)K * D * 2);       // 4 KB
    float* bsum = csq + K;                                // 2 KB (512 partials)

    float* outq = out;
    float* outi = out + (size_t)N * D;
    float* outl = outi + N;

    vq_prep<<<dim3((K * 32) / 256), dim3(256), 0, stream>>>(cw, img);
    vq_csq<<<dim3(K / 256), dim3(256), 0, stream>>>(cw, csq);

    // 32 rows/wave, 128 rows/block -> 512 blocks (2/CU), fused epilogue
    vq_main<<<dim3(N / 128), dim3(256), 0, stream>>>(inp, cw, img, csq,
                                                     outq, outi, bsum);
    vq_finalize<<<dim3(1), dim3(256), 0, stream>>>(bsum, outl, N / 128,
                                                   1.25f / ((float)N * (float)D));
}

// Round 15
// 90.638 us; speedup vs baseline: 1.2262x; 1.0655x over previous
//
#include <hip/hip_runtime.h>
#include <math.h>

typedef _Float16 v8h __attribute__((ext_vector_type(8)));
typedef float v4f __attribute__((ext_vector_type(4)));

constexpr int D      = 256;    // feature dim
constexpr int NTILE  = 64;     // 16-cand tiles (1024 / 16)
constexpr int KS     = 8;      // k-steps of 32 per tile
constexpr int TILE_B = 8192;   // bytes per tile image (16 cand x 256 d x 2B)
constexpr int TPW    = 4;      // tiles per staged window
constexpr int WIN_B  = 32768;  // staged window bytes (4 tiles)
constexpr int NWIN   = 16;     // windows (64 tiles / 4)
#define GUARD 2.0f             // packed-score gap above which approx top1 is provably np's argmin

// ---- pre-pass: codewords -> fp16 image in per-wave-read frag order ----
__global__ void vq_prep(const float* __restrict__ cw, unsigned short* __restrict__ img) {
    int gid = blockIdx.x * 256 + threadIdx.x;   // 0..32767
    int t  = gid >> 9;
    int r  = gid & 511;
    int ks = r >> 6;
    int l  = r & 63;
    int cand = t * 16 + (l & 15);
    int k0   = ks * 32 + (l >> 4) * 8;
    const float* src = cw + (size_t)cand * D + k0;
    float4 t0 = *(const float4*)(src);
    float4 t1 = *(const float4*)(src + 4);
    v8h h;
    h[0] = (_Float16)t0.x; h[1] = (_Float16)t0.y;
    h[2] = (_Float16)t0.z; h[3] = (_Float16)t0.w;
    h[4] = (_Float16)t1.x; h[5] = (_Float16)t1.y;
    h[6] = (_Float16)t1.z; h[7] = (_Float16)t1.w;
    *(v8h*)((char*)img + (size_t)gid * 16) = h;
}

// ---- codeword squared norms (fp32; IDENTICAL to the round-1/5 code that passed) ----
__global__ void vq_csq(const float* __restrict__ cw, float* __restrict__ csq) {
    int k = blockIdx.x * blockDim.x + threadIdx.x;
    const float4* p = reinterpret_cast<const float4*>(cw + (size_t)k * D);
    float s = 0.f;
    #pragma unroll 8
    for (int i = 0; i < D / 4; ++i) {
        float4 v = p[i];
        s += v.x * v.x; s += v.y * v.y; s += v.z * v.z; s += v.w * v.w;
    }
    csq[k] = s;
}

// ---- fused main: 4-tile windows (16 sync points, 8 independent MFMA chains),
// then wave-local GUARD epilogue (clear rows take approx top1; near-tie rows
// run the VERBATIM round-7 np-ordered exact 4-cand rescore); gather + write. ----
__launch_bounds__(256, 2)
__global__ void vq_main(const float* __restrict__ inp,
                        const float* __restrict__ cw,
                        const unsigned short* __restrict__ img,
                        const float* __restrict__ csq,
                        float* __restrict__ outq,
                        float* __restrict__ outi,
                        float* __restrict__ bsum) {
    __shared__ __align__(16) char smem[2][WIN_B];   // 64 KB staging
    __shared__ int4  s_pack[128];      // per-row packed top-4
    __shared__ float s_xsq[128];       // per-row exact fp32 |x|^2
    __shared__ int   s_win[128];       // per-row winner index
    __shared__ float s_l[4];

    const int tid  = threadIdx.x;
    const int lane = tid & 63;
    const int w    = tid >> 6;              // wave 0..3
    const int lr   = lane & 15;
    const int q    = lane >> 4;             // k-chunk group
    const int base = blockIdx.x * 128 + w * 32;

    // stage window 0 (tiles 0..3) FIRST so it overlaps the A-load/convert
    #pragma unroll
    for (int i = 0; i < 8; ++i) {
        int off = i * 4096 + w * 1024;
        __builtin_amdgcn_global_load_lds(
            (const __attribute__((address_space(1))) unsigned int*)((const char*)img + off + lane * 16),
            (__attribute__((address_space(3))) unsigned int*)(&smem[0][off]),
            16, 0, 0);
    }

    // load + convert A (pre-scaled by -2, exact); emit exact f32 xsq to LDS
    v8h a2[2][8];
    #pragma unroll
    for (int m = 0; m < 2; ++m) {
        const float* rp = inp + (size_t)(base + m * 16 + lr) * D + q * 8;
        float sq = 0.f;
        #pragma unroll
        for (int ks = 0; ks < KS; ++ks) {
            float4 t0 = *(const float4*)(rp + ks * 32);
            float4 t1 = *(const float4*)(rp + ks * 32 + 4);
            sq = fmaf(t0.x, t0.x, sq); sq = fmaf(t0.y, t0.y, sq);
            sq = fmaf(t0.z, t0.z, sq); sq = fmaf(t0.w, t0.w, sq);
            sq = fmaf(t1.x, t1.x, sq); sq = fmaf(t1.y, t1.y, sq);
            sq = fmaf(t1.z, t1.z, sq); sq = fmaf(t1.w, t1.w, sq);
            v8h h;
            h[0] = (_Float16)(-2.f * t0.x); h[1] = (_Float16)(-2.f * t0.y);
            h[2] = (_Float16)(-2.f * t0.z); h[3] = (_Float16)(-2.f * t0.w);
            h[4] = (_Float16)(-2.f * t1.x); h[5] = (_Float16)(-2.f * t1.y);
            h[6] = (_Float16)(-2.f * t1.z); h[7] = (_Float16)(-2.f * t1.w);
            a2[m][ks] = h;
        }
        // combine the 4 k-chunk partials (q-lanes) -> full xsq (loss-only use)
        sq += __shfl_xor(sq, 16);
        sq += __shfl_xor(sq, 32);
        if (q == 0) s_xsq[w * 32 + m * 16 + lr] = sq;
    }

    const float BIGF = __uint_as_float(0x7F000000u);
    float v1[2][4], v2[2][4];
    #pragma unroll
    for (int m = 0; m < 2; ++m)
        #pragma unroll
        for (int r = 0; r < 4; ++r) { v1[m][r] = BIGF; v2[m][r] = BIGF; }

    asm volatile("s_waitcnt vmcnt(0)" ::: "memory");   // window 0 landed
    __builtin_amdgcn_s_barrier();
    __builtin_amdgcn_sched_barrier(0);

    int cur = 0;
    for (int win = 0; win < NWIN; ++win) {
        if (win + 1 < NWIN) {   // stage next window early; overlaps compute
            const char* srct = (const char*)img + (size_t)(win + 1) * WIN_B;
            #pragma unroll
            for (int i = 0; i < 8; ++i) {
                int off = i * 4096 + w * 1024;
                __builtin_amdgcn_global_load_lds(
                    (const __attribute__((address_space(1))) unsigned int*)(srct + off + lane * 16),
                    (__attribute__((address_space(3))) unsigned int*)(&smem[cur ^ 1][off]),
                    16, 0, 0);
            }
        }

        const char* bb = smem[cur];
        // 4 tiles x 2 M-frags = 8 independent MFMA chains
        v4f acc[TPW][2];
        #pragma unroll
        for (int tt = 0; tt < TPW; ++tt) {
            float cq = csq[(win * TPW + tt) * 16 + lr] + 4096.f;
            v4f c = {cq, cq, cq, cq};
            acc[tt][0] = c; acc[tt][1] = c;
        }
        #pragma unroll
        for (int ks = 0; ks < KS; ++ks) {
            v8h b0 = *(const v8h*)(bb + 0 * TILE_B + ks * 1024 + lane * 16);
            v8h b1 = *(const v8h*)(bb + 1 * TILE_B + ks * 1024 + lane * 16);
            v8h b2 = *(const v8h*)(bb + 2 * TILE_B + ks * 1024 + lane * 16);
            v8h b3 = *(const v8h*)(bb + 3 * TILE_B + ks * 1024 + lane * 16);
            acc[0][0] = __builtin_amdgcn_mfma_f32_16x16x32_f16(a2[0][ks], b0, acc[0][0], 0, 0, 0);
            acc[1][0] = __builtin_amdgcn_mfma_f32_16x16x32_f16(a2[0][ks], b1, acc[1][0], 0, 0, 0);
            acc[2][0] = __builtin_amdgcn_mfma_f32_16x16x32_f16(a2[0][ks], b2, acc[2][0], 0, 0, 0);
            acc[3][0] = __builtin_amdgcn_mfma_f32_16x16x32_f16(a2[0][ks], b3, acc[3][0], 0, 0, 0);
            acc[0][1] = __builtin_amdgcn_mfma_f32_16x16x32_f16(a2[1][ks], b0, acc[0][1], 0, 0, 0);
            acc[1][1] = __builtin_amdgcn_mfma_f32_16x16x32_f16(a2[1][ks], b1, acc[1][1], 0, 0, 0);
            acc[2][1] = __builtin_amdgcn_mfma_f32_16x16x32_f16(a2[1][ks], b2, acc[2][1], 0, 0, 0);
            acc[3][1] = __builtin_amdgcn_mfma_f32_16x16x32_f16(a2[1][ks], b3, acc[3][1], 0, 0, 0);
        }
        // packed top-2 update (round-to-nearest monotone packing, idx in low 10b)
        #pragma unroll
        for (int tt = 0; tt < TPW; ++tt) {
            unsigned idx = (unsigned)((win * TPW + tt) * 16) | (unsigned)lr;
            #pragma unroll
            for (int m = 0; m < 2; ++m)
                #pragma unroll
                for (int r = 0; r < 4; ++r) {
                    float f = __uint_as_float(((__float_as_uint(acc[tt][m][r]) + 0x200u) & 0xFFFFFC00u) | idx);
                    float mx = fmaxf(v1[m][r], f);
                    v2[m][r] = fminf(v2[m][r], mx);
                    v1[m][r] = fminf(v1[m][r], f);
                }
        }

        asm volatile("s_waitcnt vmcnt(0)" ::: "memory");   // next window landed
        __builtin_amdgcn_s_barrier();
        __builtin_amdgcn_sched_barrier(0);
        cur ^= 1;
    }

    // bitonic merge of packed sorted-2 (padded to 4) across the 16 lanes per row
    #pragma unroll
    for (int m = 0; m < 2; ++m)
        #pragma unroll
        for (int r = 0; r < 4; ++r) {
            float L0 = v1[m][r], L1 = v2[m][r], L2 = BIGF, L3 = BIGF;
            #pragma unroll
            for (int off = 8; off; off >>= 1) {
                float P0 = __shfl_xor(L0, off, 16);
                float P1 = __shfl_xor(L1, off, 16);
                float P2 = __shfl_xor(L2, off, 16);
                float P3 = __shfl_xor(L3, off, 16);
                float M0 = fminf(L0, P3), M1 = fminf(L1, P2);
                float M2 = fminf(L2, P1), M3 = fminf(L3, P0);
                float a0 = fminf(M0, M2), c0 = fmaxf(M0, M2);
                float b0 = fminf(M1, M3), d0 = fmaxf(M1, M3);
                L0 = fminf(a0, b0); L1 = fmaxf(a0, b0);
                L2 = fminf(c0, d0); L3 = fmaxf(c0, d0);
            }
            if (lr == 0) {
                int rloc = m * 16 + q * 4 + r;         // 0..31 within wave
                s_pack[w * 32 + rloc] = make_int4(
                    (int)__float_as_uint(L0), (int)__float_as_uint(L1),
                    (int)__float_as_uint(L2), (int)__float_as_uint(L3));
            }
        }
    // wave-local LDS round-trip (writer == reader wave); compiler inserts lgkmcnt

    // ---- fused epilogue: 4 lanes per row over the wave's 32 rows ----
    const int c = lane & 3;
    float lacc = 0.f;
    #pragma unroll
    for (int h = 0; h < 2; ++h) {
        int rloc = h * 16 + (lane >> 2);               // 0..31 within wave
        int grow = base + rloc;
        int4 pk = s_pack[w * 32 + rloc];
        float L0 = __uint_as_float((unsigned)pk.x);
        float L1 = __uint_as_float((unsigned)pk.y);
        float L2 = __uint_as_float((unsigned)pk.z);
        float L3 = __uint_as_float((unsigned)pk.w);
        float xq = s_xsq[w * 32 + rloc];

        int   bi;
        float bd;
        bool rescue = (L1 - L0) < GUARD;               // uniform across the 4-lane group
        if (rescue) {
            float Lc = (c == 0) ? L0 : (c == 1) ? L1 : (c == 2) ? L2 : L3;
            int cd = (int)(__float_as_uint(Lc) & 1023u);
            const float4* xp = (const float4*)(inp + (size_t)grow * D);
            const float4* cp = (const float4*)(cw + (size_t)cd * D);
            float dot = 0.f, xsq = 0.f;
            #pragma unroll 8
            for (int i = 0; i < D / 4; ++i) {
                float4 xv = xp[i];
                float4 cv = cp[i];
                xsq = fmaf(xv.x, xv.x, xsq);
                xsq = fmaf(xv.y, xv.y, xsq);
                xsq = fmaf(xv.z, xv.z, xsq);
                xsq = fmaf(xv.w, xv.w, xsq);
                dot = fmaf(xv.x, cv.x, dot);
                dot = fmaf(xv.y, cv.y, dot);
                dot = fmaf(xv.z, cv.z, dot);
                dot = fmaf(xv.w, cv.w, dot);
            }
            float m2 = dot + dot;
            float t  = xsq - m2;
            float e  = t + csq[cd];
            bd = e; bi = cd;
            #pragma unroll
            for (int off = 1; off <= 2; off <<= 1) {
                float ev = __shfl_xor(bd, off, 4);
                int   iv = __shfl_xor(bi, off, 4);
                bool  tk = (ev < bd) || (ev == bd && iv < bi);
                bd = tk ? ev : bd;
                bi = tk ? iv : bi;
            }
        } else {
            bi = (int)(__float_as_uint(L0) & 1023u);
            bd = (L0 - 4096.f) + xq;                   // approx dist (loss only)
        }

        if (c == 0) { s_win[w * 32 + rloc] = bi; lacc += bd; }
    }

    // gather winning codewords (L2-resident) -> coalesced outq write
    #pragma unroll 4
    for (int rr = 0; rr < 32; ++rr) {
        int bw = s_win[w * 32 + rr];                   // wave-uniform broadcast
        float4 cv = *(const float4*)(cw + (size_t)bw * D + lane * 4);
        *(float4*)(outq + (size_t)(base + rr) * D + lane * 4) = cv;
        if (lane == 0) outi[base + rr] = (float)bw;
    }

    // block loss partial (deterministic)
    #pragma unroll
    for (int off = 32; off; off >>= 1) lacc += __shfl_xor(lacc, off);
    if (lane == 0) s_l[w] = lacc;
    __syncthreads();
    if (tid == 0) bsum[blockIdx.x] = s_l[0] + s_l[1] + s_l[2] + s_l[3];
}

// ---- deterministic loss reduction ----
__global__ void vq_finalize(const float* __restrict__ bsum, float* __restrict__ out_loss,
                            int nb, float scale) {
    __shared__ float s[4];
    int tid = threadIdx.x;
    float v = 0.f;
    for (int i = tid; i < nb; i += 256) v += bsum[i];
    #pragma unroll
    for (int off = 32; off; off >>= 1) v += __shfl_down(v, off, 64);
    if ((tid & 63) == 0) s[tid >> 6] = v;
    __syncthreads();
    if (tid == 0) out_loss[0] = (s[0] + s[1] + s[2] + s[3]) * scale;
}

extern "C" void kernel_launch(void* const* d_in, const int* in_sizes, int n_in,
                              void* d_out, int out_size, void* d_ws, size_t ws_size,
                              hipStream_t stream) {
    const float* inp = (const float*)d_in[0];
    const float* cw  = (const float*)d_in[1];
    float* out = (float*)d_out;
    const int N = in_sizes[0] / D;   // 65536
    const int K = in_sizes[1] / D;   // 1024

    char* ws = (char*)d_ws;
    unsigned short* img = (unsigned short*)ws;            // 512 KB fp16 image
    float* csq  = (float*)(ws + (size_t)K * D * 2);       // 4 KB
    float* bsum = csq + K;                                // 2 KB (512 partials)

    float* outq = out;
    float* outi = out + (size_t)N * D;
    float* outl = outi + N;

    vq_prep<<<dim3((K * 32) / 256), dim3(256), 0, stream>>>(cw, img);
    vq_csq<<<dim3(K / 256), dim3(256), 0, stream>>>(cw, csq);

    // 32 rows/wave, 128 rows/block -> 512 blocks (2/CU), fused epilogue
    vq_main<<<dim3(N / 128), dim3(256), 0, stream>>>(inp, cw, img, csq,
                                                     outq, outi, bsum);
    vq_finalize<<<dim3(1), dim3(256), 0, stream>>>(bsum, outl, N / 128,
                                                   1.25f / ((float)N * (float)D));
}